// Round 3
// baseline (114.830 us; speedup 1.0000x reference)
//
#include <hip/hip_runtime.h>
#include <hip/hip_bf16.h>
#include <math.h>

// Collapsed math (softmax over the size-1 summary axis == 1 identically, so
// q/Wq/Wk/bias-MLP/mask-bias are dead code):
//   summary[bn,:] = sum_t m*x / max(sum_t m, 1e-6)
//   v[bn,:]       = summary @ Wv + bv
//   rf[bn,t]      = [dx,dy,dz,||d||,||d||^2] vs masked-mean position
//   rel_val       = gelu_exact(rf @ Vw1 + Vb1) @ Vw2 + Vb2   (bf16 MFMA)
//   out[bn,t,:]   = x[bn,t,:] + v[bn,:] + rel_val[bn,t,:]
//
// Round-3 structure: split for occupancy/overlap (round-2 fused kernel was
// 1 block/CU and phase-serialized: VALUBusy 8.8%, HBM 10%).
//   k_sum  : 512 blocks x 256 thr, ~10 KB LDS -> 8 blocks/CU, streams x once.
//   k_main : (2,512) x 512 thr, 40 KB LDS, VGPR<=128 -> 2 blocks/CU,
//            hidden-MLP + MFMA GEMM + epilogue (x re-read hits L3).

#define BN_TOT 512
#define T_DIM 256
#define D_DIM 256
#define HID 128

typedef __attribute__((ext_vector_type(8))) short short8v;
typedef __attribute__((ext_vector_type(4))) float f32x4;

static __device__ __forceinline__ ushort f2bf(float f) {
    __hip_bfloat16 h = __float2bfloat16(f);
    return *reinterpret_cast<ushort*>(&h);
}

// ---- prep: Vw2 [128][256] f32 -> Vw2t [256][128] bf16 (transposed) ----
__global__ __launch_bounds__(128) void k_prep(const float* __restrict__ Vw2,
                                              ushort* __restrict__ Vw2t) {
    const int d = blockIdx.x;      // 0..255
    const int k = threadIdx.x;     // 0..127
    Vw2t[d * HID + k] = f2bf(Vw2[k * D_DIM + d]);
}

// ---- K1: per-bn masked means + v = summary @ Wv + bv + Vb2 ----
__global__ __launch_bounds__(256, 8) void k_sum(
    const float* __restrict__ x,      // [BN,T,D]
    const int* __restrict__ masks,    // [BN,T]
    const float* __restrict__ pos,    // [BN,T,3]
    const float* __restrict__ Wv,     // [D,D]
    const float* __restrict__ bv,     // [D]
    const float* __restrict__ Vb2,    // [D]
    float* __restrict__ v_ws,         // [BN,D]
    float* __restrict__ ps_ws)        // [BN,4]
{
    __shared__ float s_m[256];
    __shared__ float s_red[4 * 256];
    __shared__ float s_part[4 * 256];
    __shared__ float s_sum[256];

    const int bn = blockIdx.x, tid = threadIdx.x;
    const float* xb = x + (size_t)bn * T_DIM * D_DIM;

    {
        float m = (float)masks[bn * T_DIM + tid];
        s_m[tid] = m;
        const float* pp = pos + ((size_t)bn * T_DIM + tid) * 3;
        s_red[0 * 256 + tid] = m;
        s_red[1 * 256 + tid] = m * pp[0];
        s_red[2 * 256 + tid] = m * pp[1];
        s_red[3 * 256 + tid] = m * pp[2];
    }
    __syncthreads();

    // masked column sums of x: 64 float4-chunks x 4 token-groups of 64
    {
        const int dq = tid & 63, tq = tid >> 6;
        float4 a = make_float4(0.f, 0.f, 0.f, 0.f);
        const float* px = xb + (size_t)tq * 64 * D_DIM + dq * 4;
        #pragma unroll 8
        for (int i = 0; i < 64; ++i) {
            float m = s_m[tq * 64 + i];
            float4 xv = *reinterpret_cast<const float4*>(px + i * D_DIM);
            a.x += m * xv.x; a.y += m * xv.y; a.z += m * xv.z; a.w += m * xv.w;
        }
        *reinterpret_cast<float4*>(s_part + tq * 256 + dq * 4) = a;
    }
    __syncthreads();

    for (int off = 128; off > 0; off >>= 1) {
        if (tid < off) {
            s_red[0 * 256 + tid] += s_red[0 * 256 + tid + off];
            s_red[1 * 256 + tid] += s_red[1 * 256 + tid + off];
            s_red[2 * 256 + tid] += s_red[2 * 256 + tid + off];
            s_red[3 * 256 + tid] += s_red[3 * 256 + tid + off];
        }
        __syncthreads();
    }
    const float inv = 1.0f / fmaxf(s_red[0], 1e-6f);
    if (tid < 3) ps_ws[bn * 4 + tid] = s_red[(tid + 1) * 256] * inv;

    s_sum[tid] = (s_part[0 * 256 + tid] + s_part[1 * 256 + tid] +
                  s_part[2 * 256 + tid] + s_part[3 * 256 + tid]) * inv;
    __syncthreads();

    // v = summary @ Wv : 64 float4-chunks x 4 k-groups of 64
    {
        const int dq = tid & 63, kq = tid >> 6;
        float4 a = make_float4(0.f, 0.f, 0.f, 0.f);
        #pragma unroll 8
        for (int i = 0; i < 64; ++i) {
            const int k = kq * 64 + i;
            float sc = s_sum[k];
            float4 w = *reinterpret_cast<const float4*>(Wv + (size_t)k * D_DIM + dq * 4);
            a.x += sc * w.x; a.y += sc * w.y; a.z += sc * w.z; a.w += sc * w.w;
        }
        *reinterpret_cast<float4*>(s_part + kq * 256 + dq * 4) = a;
    }
    __syncthreads();
    v_ws[bn * D_DIM + tid] = s_part[0 * 256 + tid] + s_part[1 * 256 + tid] +
                             s_part[2 * 256 + tid] + s_part[3 * 256 + tid] +
                             bv[tid] + Vb2[tid];
}

// ---- K2: hidden MLP + MFMA GEMM + residual epilogue, per (token-half, bn) ----
__global__ __launch_bounds__(512, 4) void k_main(
    const float* __restrict__ x,
    const float* __restrict__ pos,
    const float* __restrict__ Vw1,    // [5,128]
    const float* __restrict__ Vb1,    // [128]
    const ushort* __restrict__ Vw2t,  // [256][128] bf16
    const float* __restrict__ v_ws,   // [BN,256] (= v + bv + Vb2)
    const float* __restrict__ ps_ws,  // [BN,4]
    float* __restrict__ out)
{
    __shared__ float s_rf[128 * 6];
    __shared__ float s_w1[5 * 128];
    __shared__ float s_b1[128];
    __shared__ float s_vb[256];
    __shared__ unsigned char s_hid[128 * HID * 2];   // 32 KB bf16, XOR-swizzled

    const int half = blockIdx.x;          // token half: 0 or 1
    const int bn   = blockIdx.y;
    const int tid  = threadIdx.x;
    const int t0   = half * 128;

    if (tid < 256) s_vb[tid] = v_ws[bn * D_DIM + tid];
    for (int i = tid; i < 640; i += 512) s_w1[i] = Vw1[i];
    if (tid < 128) s_b1[tid] = Vb1[tid];

    const float psx = ps_ws[bn * 4 + 0];
    const float psy = ps_ws[bn * 4 + 1];
    const float psz = ps_ws[bn * 4 + 2];
    if (tid < 128) {
        const float* pp = pos + ((size_t)bn * T_DIM + t0 + tid) * 3;
        float dx = pp[0] - psx, dy = pp[1] - psy, dz = pp[2] - psz;
        float d2 = dx * dx + dy * dy + dz * dz;
        s_rf[tid * 6 + 0] = dx; s_rf[tid * 6 + 1] = dy; s_rf[tid * 6 + 2] = dz;
        s_rf[tid * 6 + 3] = sqrtf(d2); s_rf[tid * 6 + 4] = d2;
    }
    __syncthreads();

    // hidden = gelu_exact(rf @ Vw1 + Vb1) -> bf16 LDS (swizzled)
    {
        const int cg = tid & 15;          // 8 channels: c0..c0+7
        const int c0 = cg * 8;
        float wv[5][8], bb[8];
        #pragma unroll
        for (int e = 0; e < 5; ++e)
            #pragma unroll
            for (int j = 0; j < 8; ++j) wv[e][j] = s_w1[e * HID + c0 + j];
        #pragma unroll
        for (int j = 0; j < 8; ++j) bb[j] = s_b1[c0 + j];

        #pragma unroll
        for (int s = 0; s < 4; ++s) {
            const int tok = (tid >> 4) + s * 32;    // local 0..127
            const float* rf = s_rf + tok * 6;
            const float dx = rf[0], dy = rf[1], dz = rf[2], dd = rf[3], d2 = rf[4];
            uint pk[4];
            #pragma unroll
            for (int jj = 0; jj < 4; ++jj) {
                float g[2];
                #pragma unroll
                for (int h = 0; h < 2; ++h) {
                    const int j = jj * 2 + h;
                    float z = bb[j] + dx * wv[0][j] + dy * wv[1][j] + dz * wv[2][j]
                                    + dd * wv[3][j] + d2 * wv[4][j];
                    g[h] = 0.5f * z * (1.0f + erff(z * 0.70710678118654752f));
                }
                pk[jj] = (uint)f2bf(g[0]) | ((uint)f2bf(g[1]) << 16);
            }
            int byte = tok * 256 + cg * 16;
            byte ^= (tok & 7) << 4;
            *reinterpret_cast<uint4*>(s_hid + byte) = make_uint4(pk[0], pk[1], pk[2], pk[3]);
        }
    }
    __syncthreads();

    // GEMM: rel_val[128 x 256] = hidden[128 x 128] @ Vw2t^T (8 waves, 64x64 tiles)
    const int l  = tid & 63;
    const int wid = tid >> 6;
    const int wr = wid & 1;               // token quarter (64 tokens)
    const int wc = wid >> 1;              // d chunk (64 cols)

    f32x4 acc[4][4];
    #pragma unroll
    for (int m = 0; m < 4; ++m)
        #pragma unroll
        for (int n = 0; n < 4; ++n) acc[m][n] = (f32x4){0.f, 0.f, 0.f, 0.f};

    const ushort* bbase = Vw2t + ((size_t)(wc * 64 + (l & 15))) * HID + ((l >> 4) * 8);
    const int col16 = (l >> 4) * 16;

    #pragma unroll
    for (int ks = 0; ks < 4; ++ks) {
        short8v bfr[4];
        #pragma unroll
        for (int n = 0; n < 4; ++n)
            bfr[n] = *reinterpret_cast<const short8v*>(bbase + n * 16 * HID + ks * 32);
        short8v afr[4];
        #pragma unroll
        for (int m = 0; m < 4; ++m) {
            const int tok = wr * 64 + m * 16 + (l & 15);
            int byte = tok * 256 + ks * 64 + col16;
            byte ^= (tok & 7) << 4;
            afr[m] = *reinterpret_cast<const short8v*>(s_hid + byte);
        }
        #pragma unroll
        for (int m = 0; m < 4; ++m)
            #pragma unroll
            for (int n = 0; n < 4; ++n)
                acc[m][n] = __builtin_amdgcn_mfma_f32_16x16x32_bf16(
                    afr[m], bfr[n], acc[m][n], 0, 0, 0);
    }

    // epilogue: out = x + (v+bv+Vb2) + rel_val
    #pragma unroll
    for (int m = 0; m < 4; ++m) {
        const int tokl = wr * 64 + m * 16 + (l >> 4) * 4;
        const float* xr   = x   + ((size_t)bn * T_DIM + t0 + tokl) * D_DIM;
        float*       orow = out + ((size_t)bn * T_DIM + t0 + tokl) * D_DIM;
        #pragma unroll
        for (int n = 0; n < 4; ++n) {
            const int d = wc * 64 + n * 16 + (l & 15);
            const float vb = s_vb[d];
            #pragma unroll
            for (int r = 0; r < 4; ++r) {
                orow[r * D_DIM + d] = xr[r * D_DIM + d] + vb + acc[m][n][r];
            }
        }
    }
}

extern "C" void kernel_launch(void* const* d_in, const int* in_sizes, int n_in,
                              void* d_out, int out_size, void* d_ws, size_t ws_size,
                              hipStream_t stream) {
    const float* x     = (const float*)d_in[0];
    // d_in[1] = sum_token (unused by reference)
    const int*   masks = (const int*)d_in[2];
    const float* pos   = (const float*)d_in[3];
    // d_in[4..7] = Wq,bq,Wk,bk (dead: softmax over size-1 axis == 1)
    const float* Wv    = (const float*)d_in[8];
    const float* bv    = (const float*)d_in[9];
    // d_in[10..13] = bias-MLP (dead)
    const float* Vw1   = (const float*)d_in[14];
    const float* Vb1   = (const float*)d_in[15];
    const float* Vw2   = (const float*)d_in[16];
    const float* Vb2   = (const float*)d_in[17];
    float* out = (float*)d_out;

    ushort* Vw2t = (ushort*)d_ws;                       // 64 KB
    float*  v_ws = (float*)(Vw2t + D_DIM * HID);        // [BN,256] 512 KB
    float*  ps_ws = v_ws + BN_TOT * D_DIM;              // [BN,4]

    k_prep<<<D_DIM, HID, 0, stream>>>(Vw2, Vw2t);
    k_sum<<<BN_TOT, 256, 0, stream>>>(x, masks, pos, Wv, bv, Vb2, v_ws, ps_ws);
    k_main<<<dim3(2, BN_TOT), 512, 0, stream>>>(x, pos, Vw1, Vb1, Vw2t,
                                                v_ws, ps_ws, out);
}

// Round 4
// 97.164 us; speedup vs baseline: 1.1818x; 1.1818x over previous
//
#include <hip/hip_runtime.h>
#include <hip/hip_bf16.h>
#include <math.h>

// Collapsed math (softmax over the size-1 summary axis == 1 identically, so
// q/Wq/Wk/bias-MLP/mask-bias are dead code):
//   summary[bn,:] = sum_t m*x / max(sum_t m, 1e-6)
//   v[bn,:]       = summary @ Wv + bv
//   rf[bn,t]      = [dx,dy,dz,||d||,||d||^2] vs masked-mean position
//   rel_val       = gelu_exact(rf @ Vw1 + Vb1) @ Vw2 + Vb2   (bf16 MFMA)
//   out[bn,t,:]   = x[bn,t,:] + v[bn,:] + rel_val[bn,t,:]
//
// Round-4: swapped-operand MFMA (D = W_frag @ hid_frag = rel_val^T) so each
// lane holds 4 CONSECUTIVE d per token -> float4 epilogue (round-3 epilogue
// was scalar 4B: 256B/wave-instr, VALUBusy 12%, HBM 11%). 64-token blocks
// (grid 2048) for occupancy/overlap.

#define BN_TOT 512
#define T_DIM 256
#define D_DIM 256
#define HID 128

typedef __attribute__((ext_vector_type(8))) short short8v;
typedef __attribute__((ext_vector_type(4))) float f32x4;

static __device__ __forceinline__ ushort f2bf(float f) {
    __hip_bfloat16 h = __float2bfloat16(f);
    return *reinterpret_cast<ushort*>(&h);
}

// ---- prep: Vw2 [128][256] f32 -> Vw2t [256][128] bf16 (transposed) ----
__global__ __launch_bounds__(128) void k_prep(const float* __restrict__ Vw2,
                                              ushort* __restrict__ Vw2t) {
    const int d = blockIdx.x;      // 0..255
    const int k = threadIdx.x;     // 0..127
    Vw2t[d * HID + k] = f2bf(Vw2[k * D_DIM + d]);
}

// ---- K1: per-bn masked means + v = summary @ Wv + bv + Vb2 ----
__global__ __launch_bounds__(512, 8) void k_sum(
    const float* __restrict__ x,      // [BN,T,D]
    const int* __restrict__ masks,    // [BN,T]
    const float* __restrict__ pos,    // [BN,T,3]
    const float* __restrict__ Wv,     // [D,D]
    const float* __restrict__ bv,     // [D]
    const float* __restrict__ Vb2,    // [D]
    float* __restrict__ v_ws,         // [BN,D]
    float* __restrict__ ps_ws)        // [BN,4]
{
    __shared__ float s_m[256];
    __shared__ float s_red[4 * 256];
    __shared__ float s_part[8 * 256];
    __shared__ float s_sum[256];

    const int bn = blockIdx.x, tid = threadIdx.x;
    const float* xb = x + (size_t)bn * T_DIM * D_DIM;

    if (tid < 256) {
        float m = (float)masks[bn * T_DIM + tid];
        s_m[tid] = m;
        const float* pp = pos + ((size_t)bn * T_DIM + tid) * 3;
        s_red[0 * 256 + tid] = m;
        s_red[1 * 256 + tid] = m * pp[0];
        s_red[2 * 256 + tid] = m * pp[1];
        s_red[3 * 256 + tid] = m * pp[2];
    }
    __syncthreads();

    // masked column sums of x: 64 float4-chunks x 8 token-groups of 32
    {
        const int dq = tid & 63, tq = tid >> 6;
        float4 a = make_float4(0.f, 0.f, 0.f, 0.f);
        const float* px = xb + (size_t)tq * 32 * D_DIM + dq * 4;
        #pragma unroll 8
        for (int i = 0; i < 32; ++i) {
            float m = s_m[tq * 32 + i];
            float4 xv = *reinterpret_cast<const float4*>(px + i * D_DIM);
            a.x += m * xv.x; a.y += m * xv.y; a.z += m * xv.z; a.w += m * xv.w;
        }
        *reinterpret_cast<float4*>(s_part + tq * 256 + dq * 4) = a;
    }
    __syncthreads();

    for (int off = 128; off > 0; off >>= 1) {
        if (tid < off) {
            s_red[0 * 256 + tid] += s_red[0 * 256 + tid + off];
            s_red[1 * 256 + tid] += s_red[1 * 256 + tid + off];
            s_red[2 * 256 + tid] += s_red[2 * 256 + tid + off];
            s_red[3 * 256 + tid] += s_red[3 * 256 + tid + off];
        }
        __syncthreads();
    }
    const float inv = 1.0f / fmaxf(s_red[0], 1e-6f);
    if (tid < 3) ps_ws[bn * 4 + tid] = s_red[(tid + 1) * 256] * inv;

    if (tid < 256) {
        float s = 0.f;
        #pragma unroll
        for (int q = 0; q < 8; ++q) s += s_part[q * 256 + tid];
        s_sum[tid] = s * inv;
    }
    __syncthreads();

    // v = summary @ Wv : 64 float4-chunks x 8 k-groups of 32
    {
        const int dq = tid & 63, kq = tid >> 6;
        float4 a = make_float4(0.f, 0.f, 0.f, 0.f);
        #pragma unroll 8
        for (int i = 0; i < 32; ++i) {
            const int k = kq * 32 + i;
            float sc = s_sum[k];
            float4 w = *reinterpret_cast<const float4*>(Wv + (size_t)k * D_DIM + dq * 4);
            a.x += sc * w.x; a.y += sc * w.y; a.z += sc * w.z; a.w += sc * w.w;
        }
        *reinterpret_cast<float4*>(s_part + kq * 256 + dq * 4) = a;
    }
    __syncthreads();
    if (tid < 256) {
        float r = bv[tid] + Vb2[tid];
        #pragma unroll
        for (int q = 0; q < 8; ++q) r += s_part[q * 256 + tid];
        v_ws[bn * D_DIM + tid] = r;
    }
}

// ---- K2: hidden MLP + MFMA GEMM + float4 residual epilogue ----
// grid (4, 512): 64-token tile per block; 256 threads (4 waves).
__global__ __launch_bounds__(256, 4) void k_main(
    const float* __restrict__ x,
    const float* __restrict__ pos,
    const float* __restrict__ Vw1,    // [5,128]
    const float* __restrict__ Vb1,    // [128]
    const ushort* __restrict__ Vw2t,  // [256][128] bf16
    const float* __restrict__ v_ws,   // [BN,256] (= v + bv + Vb2)
    const float* __restrict__ ps_ws,  // [BN,4]
    float* __restrict__ out)
{
    __shared__ float s_rf[64 * 6];                  // 1.5 KB
    __shared__ float s_w1[5 * 128];                 // 2.5 KB
    __shared__ float s_b1[128];                     // 0.5 KB
    __shared__ float s_vb[256];                     // 1 KB
    __shared__ unsigned char s_hid[64 * HID * 2];   // 16 KB bf16, XOR-swizzled

    const int tg  = blockIdx.x;           // token group of 64
    const int bn  = blockIdx.y;
    const int tid = threadIdx.x;
    const int t0  = tg * 64;

    s_vb[tid] = v_ws[bn * D_DIM + tid];
    if (tid < 256) { /* all */ }
    for (int i = tid; i < 640; i += 256) s_w1[i] = Vw1[i];
    if (tid < 128) s_b1[tid] = Vb1[tid];

    const float psx = ps_ws[bn * 4 + 0];
    const float psy = ps_ws[bn * 4 + 1];
    const float psz = ps_ws[bn * 4 + 2];
    if (tid < 64) {
        const float* pp = pos + ((size_t)bn * T_DIM + t0 + tid) * 3;
        float dx = pp[0] - psx, dy = pp[1] - psy, dz = pp[2] - psz;
        float d2 = dx * dx + dy * dy + dz * dz;
        s_rf[tid * 6 + 0] = dx; s_rf[tid * 6 + 1] = dy; s_rf[tid * 6 + 2] = dz;
        s_rf[tid * 6 + 3] = sqrtf(d2); s_rf[tid * 6 + 4] = d2;
    }
    __syncthreads();

    // hidden = gelu_exact(rf @ Vw1 + Vb1) -> bf16 LDS (swizzled, [tok][128ch])
    {
        const int cg = tid & 15;          // 8 channels: c0..c0+7
        const int c0 = cg * 8;
        float wv[5][8], bb[8];
        #pragma unroll
        for (int e = 0; e < 5; ++e)
            #pragma unroll
            for (int j = 0; j < 8; ++j) wv[e][j] = s_w1[e * HID + c0 + j];
        #pragma unroll
        for (int j = 0; j < 8; ++j) bb[j] = s_b1[c0 + j];

        #pragma unroll
        for (int s = 0; s < 4; ++s) {
            const int tok = (tid >> 4) + s * 16;    // local 0..63
            const float* rf = s_rf + tok * 6;
            const float dx = rf[0], dy = rf[1], dz = rf[2], dd = rf[3], d2 = rf[4];
            uint pk[4];
            #pragma unroll
            for (int jj = 0; jj < 4; ++jj) {
                float g[2];
                #pragma unroll
                for (int h = 0; h < 2; ++h) {
                    const int j = jj * 2 + h;
                    float z = bb[j] + dx * wv[0][j] + dy * wv[1][j] + dz * wv[2][j]
                                    + dd * wv[3][j] + d2 * wv[4][j];
                    g[h] = 0.5f * z * (1.0f + erff(z * 0.70710678118654752f));
                }
                pk[jj] = (uint)f2bf(g[0]) | ((uint)f2bf(g[1]) << 16);
            }
            int byte = tok * 256 + cg * 16;
            byte ^= (tok & 15) << 4;
            *reinterpret_cast<uint4*>(s_hid + byte) = make_uint4(pk[0], pk[1], pk[2], pk[3]);
        }
    }
    __syncthreads();

    // GEMM (operand-swapped): D = Wfrag @ hidfrag = rel_val^T.
    // Lane l of wave wc: tok = m*16 + (l&15), d = wc*64 + n*16 + 4*(l>>4) + r
    // -> 4 consecutive d per lane -> float4 epilogue.
    const int l  = tid & 63;
    const int wc = tid >> 6;              // d quarter (64 cols)

    f32x4 acc[4][4];
    #pragma unroll
    for (int m = 0; m < 4; ++m)
        #pragma unroll
        for (int n = 0; n < 4; ++n) acc[m][n] = (f32x4){0.f, 0.f, 0.f, 0.f};

    const ushort* bbase = Vw2t + ((size_t)(wc * 64 + (l & 15))) * HID + ((l >> 4) * 8);
    const int koff16 = (l >> 4) * 16;     // byte offset of this lane's k-slice

    #pragma unroll
    for (int ks = 0; ks < 4; ++ks) {
        short8v wfr[4];
        #pragma unroll
        for (int n = 0; n < 4; ++n)
            wfr[n] = *reinterpret_cast<const short8v*>(bbase + n * 16 * HID + ks * 32);
        short8v hfr[4];
        #pragma unroll
        for (int m = 0; m < 4; ++m) {
            const int tok = m * 16 + (l & 15);
            int byte = tok * 256 + ks * 64 + koff16;
            byte ^= (tok & 15) << 4;
            hfr[m] = *reinterpret_cast<const short8v*>(s_hid + byte);
        }
        #pragma unroll
        for (int m = 0; m < 4; ++m)
            #pragma unroll
            for (int n = 0; n < 4; ++n)
                acc[m][n] = __builtin_amdgcn_mfma_f32_16x16x32_bf16(
                    wfr[n], hfr[m], acc[m][n], 0, 0, 0);
    }

    // epilogue: out = x + (v+bv+Vb2) + rel_val  (float4 throughout)
    #pragma unroll
    for (int m = 0; m < 4; ++m) {
        const int tok = m * 16 + (l & 15);
        const float* xr   = x   + ((size_t)bn * T_DIM + t0 + tok) * D_DIM;
        float*       orow = out + ((size_t)bn * T_DIM + t0 + tok) * D_DIM;
        #pragma unroll
        for (int n = 0; n < 4; ++n) {
            const int d0 = wc * 64 + n * 16 + ((l >> 4) << 2);
            float4 xv  = *reinterpret_cast<const float4*>(xr + d0);
            float4 vb4 = *reinterpret_cast<const float4*>(s_vb + d0);
            float4 o;
            o.x = xv.x + vb4.x + acc[m][n][0];
            o.y = xv.y + vb4.y + acc[m][n][1];
            o.z = xv.z + vb4.z + acc[m][n][2];
            o.w = xv.w + vb4.w + acc[m][n][3];
            *reinterpret_cast<float4*>(orow + d0) = o;
        }
    }
}

extern "C" void kernel_launch(void* const* d_in, const int* in_sizes, int n_in,
                              void* d_out, int out_size, void* d_ws, size_t ws_size,
                              hipStream_t stream) {
    const float* x     = (const float*)d_in[0];
    // d_in[1] = sum_token (unused by reference)
    const int*   masks = (const int*)d_in[2];
    const float* pos   = (const float*)d_in[3];
    // d_in[4..7] = Wq,bq,Wk,bk (dead: softmax over size-1 axis == 1)
    const float* Wv    = (const float*)d_in[8];
    const float* bv    = (const float*)d_in[9];
    // d_in[10..13] = bias-MLP (dead)
    const float* Vw1   = (const float*)d_in[14];
    const float* Vb1   = (const float*)d_in[15];
    const float* Vw2   = (const float*)d_in[16];
    const float* Vb2   = (const float*)d_in[17];
    float* out = (float*)d_out;

    ushort* Vw2t = (ushort*)d_ws;                       // 64 KB
    float*  v_ws = (float*)(Vw2t + D_DIM * HID);        // [BN,256] 512 KB
    float*  ps_ws = v_ws + BN_TOT * D_DIM;              // [BN,4]

    k_prep<<<D_DIM, HID, 0, stream>>>(Vw2, Vw2t);
    k_sum<<<BN_TOT, 512, 0, stream>>>(x, masks, pos, Wv, bv, Vb2, v_ws, ps_ws);
    k_main<<<dim3(4, BN_TOT), 256, 0, stream>>>(x, pos, Vw1, Vb1, Vw2t,
                                                v_ws, ps_ws, out);
}